// Round 5
// baseline (379.728 us; speedup 1.0000x reference)
//
#include <hip/hip_runtime.h>

#define Bx 8
#define Nx 256
#define Lx 48
#define Fx 96
#define KP 104     // padded K stride in bf16 units (208 B, 16B-aligned)

typedef __attribute__((ext_vector_type(8))) short bf16x8;
typedef __attribute__((ext_vector_type(4))) float f32x4;

__device__ __forceinline__ unsigned short f2bf(float f) {
    unsigned int u = __float_as_uint(f);
    u += 0x7fffu + ((u >> 16) & 1u);       // RNE
    return (unsigned short)(u >> 16);
}
// HW packed fp32->bf16 (RNE): lo = a, hi = b.
__device__ __forceinline__ unsigned int cvt_pk_bf16(float a, float b) {
    unsigned int r;
    asm("v_cvt_pk_bf16_f32 %0, %1, %2" : "=v"(r) : "v"(a), "v"(b));
    return r;
}

// ---------------------------------------------------------------------------
// kA: SINGLE pass over x (round-3 proven version).  Block roles:
//  role R (blk < 512): block = (b, 4-i-chunk). float4-vectorized read of the
//    4 rows; computes rowsum (LDS reduce), diag, trace/totsum (atomics, tiny),
//    and a per-block colsum PARTIAL tile written with plain coalesced stores
//    (part[ic*8+b][j*48+l]).  No colsum atomics at all.
//  role W (512..563): bf16 repack of w11/w12 into wt[f][KP].
// trace/totsum (3 KB) must be zeroed first.
// ---------------------------------------------------------------------------
__global__ __launch_bounds__(192) void kA_fused(const float* __restrict__ x,
                                                const float* __restrict__ w,
                                                float* __restrict__ rowsum,
                                                float* __restrict__ part,
                                                float* __restrict__ diagv,
                                                float* __restrict__ trace,
                                                float* __restrict__ totsum,
                                                unsigned short* __restrict__ wt) {
    const int blk = blockIdx.x;
    const int t = threadIdx.x;
    if (blk < 512) {
        const int b  = blk >> 6;
        const int ic = blk & 63;
        const int i0 = ic * 4;
        // thread -> (jg, l-quad): stride 192 floats * 4 = 768 = 16*48, so each
        // thread's l-quad is CONSTANT: l4 = 4*(t%12), j = (t/12) + 16*it.
        const int jg = t / 12;
        const int l4 = (t % 12) * 4;
        const size_t xb = ((size_t)(b * Nx + i0)) * Nx * Lx;
        float* __restrict__ pp = part + ((size_t)(ic * 8 + b)) * (Nx * Lx);

        float4 r0 = {0.f,0.f,0.f,0.f}, r1 = r0, r2 = r0, r3 = r0;
        #pragma unroll
        for (int it = 0; it < 16; ++it) {
            const int j = jg + 16 * it;
            const size_t off = (size_t)j * Lx + l4;
            const float4 v0 = *(const float4*)(x + xb + off);
            const float4 v1 = *(const float4*)(x + xb + (size_t)Nx * Lx + off);
            const float4 v2 = *(const float4*)(x + xb + 2 * (size_t)Nx * Lx + off);
            const float4 v3 = *(const float4*)(x + xb + 3 * (size_t)Nx * Lx + off);
            r0.x += v0.x; r0.y += v0.y; r0.z += v0.z; r0.w += v0.w;
            r1.x += v1.x; r1.y += v1.y; r1.z += v1.z; r1.w += v1.w;
            r2.x += v2.x; r2.y += v2.y; r2.z += v2.z; r2.w += v2.w;
            r3.x += v3.x; r3.y += v3.y; r3.z += v3.z; r3.w += v3.w;
            float4 cs;
            cs.x = (v0.x + v1.x) + (v2.x + v3.x);
            cs.y = (v0.y + v1.y) + (v2.y + v3.y);
            cs.z = (v0.z + v1.z) + (v2.z + v3.z);
            cs.w = (v0.w + v1.w) + (v2.w + v3.w);
            *(float4*)(pp + off) = cs;
        }
        // rowsum reduction: red[row][thread] float4, then (row,l) threads sum 16 jg's
        __shared__ float4 red[768];
        red[        t] = r0;
        red[192  + t] = r1;
        red[384  + t] = r2;
        red[576  + t] = r3;
        __syncthreads();
        {
            const int r = t / 48, l = t % 48;
            const float* rr = (const float*)(red + r * 192);
            float s = 0.f;
            #pragma unroll
            for (int g = 0; g < 16; ++g)
                s += rr[(g * 12 + (l >> 2)) * 4 + (l & 3)];
            const size_t ri = ((size_t)(b * Nx + i0 + r)) * Lx + l;
            rowsum[ri] = s;
            atomicAdd(totsum + b * Lx + l, s);
            const float dv = x[(((size_t)(b * Nx + i0 + r)) * Nx + (i0 + r)) * Lx + l];
            diagv[ri] = dv;
            atomicAdd(trace + b * Lx + l, dv);
        }
    } else {
        // ---- w role: 52 blocks * 192 = 9984 = Fx*KP exactly
        const int idx = (blk - 512) * 192 + t;
        const int f = idx / KP, kk = idx % KP;
        float v = 0.f;
        if (kk < 48)      v = w[12 * Lx * Fx + kk * Fx + f];
        else if (kk < 96) v = w[11 * Lx * Fx + (kk - 48) * Fx + f];
        wt[idx] = f2bf(v);
    }
}

// ---------------------------------------------------------------------------
// K2: per-(b,n) f-vectors (fp32 exact, round-3 proven version). Prologue
// reduces the 64 colsum partials for this block's 4 n-rows into LDS;
// colsum never exists globally.
// ---------------------------------------------------------------------------
__global__ __launch_bounds__(192) void k2_vectors(const float* __restrict__ w,
                                                  const float* __restrict__ rowsum,
                                                  const float* __restrict__ part,
                                                  const float* __restrict__ diagv,
                                                  const float* __restrict__ trace,
                                                  const float* __restrict__ totsum,
                                                  float* __restrict__ add_i,
                                                  float* __restrict__ add_j,
                                                  float* __restrict__ add_d) {
    const int blk = blockIdx.x;            // 0..511
    const int t = threadIdx.x;             // 0..191
    const int b  = blk >> 6;
    const int n0 = (blk & 63) * 4;
    __shared__ float csh[192];             // colsum for the block's 4 rows
    {
        const size_t e0 = (size_t)n0 * Lx + t;
        float s = 0.f;
        #pragma unroll 8
        for (int ic = 0; ic < 64; ++ic)
            s += part[((size_t)(ic * 8 + b)) * (Nx * Lx) + e0];
        csh[t] = s;
    }
    __syncthreads();

    const int f  = t % Fx;
    const int nh = t / Fx;                 // 0 or 1
    const int nb = b * Nx + n0 + nh * 2;   // first of this thread's 2 n-rows
    const float* trP = trace  + b * Lx;
    const float* tsP = totsum + b * Lx;

    float ai[2] = {0.f, 0.f}, aj[2] = {0.f, 0.f}, ad[2] = {0.f, 0.f};
    float sd = 0.f, si = 0.f;
    for (int l = 0; l < Lx; ++l) {
        const float* wl = w + (size_t)l * Fx + f;
        const float w0  = wl[0];
        const float w1  = wl[1  * Lx * Fx];
        const float w2  = wl[2  * Lx * Fx];
        const float w3  = wl[3  * Lx * Fx];
        const float w4  = wl[4  * Lx * Fx];
        const float w5  = wl[5  * Lx * Fx];
        const float w6  = wl[6  * Lx * Fx];
        const float w7  = wl[7  * Lx * Fx];
        const float w8  = wl[8  * Lx * Fx];
        const float w9  = wl[9  * Lx * Fx];
        const float w10 = wl[10 * Lx * Fx];
        const float w13 = wl[13 * Lx * Fx];
        const float w14 = wl[14 * Lx * Fx];
        const float tr = trP[l], ts = tsP[l];
        sd = fmaf(tr, w3,  sd); sd = fmaf(ts, w4,  sd);
        si = fmaf(tr, w13, si); si = fmaf(ts, w14, si);
        #pragma unroll
        for (int nn = 0; nn < 2; ++nn) {
            const size_t ix = (size_t)(nb + nn) * Lx + l;
            const float d = diagv[ix], r = rowsum[ix];
            const float c = csh[(nh * 2 + nn) * Lx + l];
            ad[nn] = fmaf(d, w0, ad[nn]); ad[nn] = fmaf(r, w1, ad[nn]); ad[nn] = fmaf(c, w2,  ad[nn]);
            aj[nn] = fmaf(d, w5, aj[nn]); aj[nn] = fmaf(r, w6, aj[nn]); aj[nn] = fmaf(c, w7,  aj[nn]);
            ai[nn] = fmaf(d, w8, ai[nn]); ai[nn] = fmaf(r, w9, ai[nn]); ai[nn] = fmaf(c, w10, ai[nn]);
        }
    }
    #pragma unroll
    for (int nn = 0; nn < 2; ++nn) {
        const size_t idx = (size_t)(nb + nn) * Fx + f;
        add_d[idx] = ad[nn] + sd;
        add_j[idx] = aj[nn];
        add_i[idx] = ai[nn] + si;
    }
}

// ---------------------------------------------------------------------------
// K3: MFMA dense pass, mirror-pair reuse, swapped operand order (A = w-frag,
// B = x-frag) -> float4 NT epilogue.  NEW: w-fragments read DIRECTLY from
// global wt (20 KB, L2-resident broadcast, identical across all blocks) —
// no Bl LDS tile, no staging loop: LDS 33 KB -> 13 KB, 18 ds_read_b128 and
// 1248 stage loads removed per block; barrier only guards the A tile.
// ---------------------------------------------------------------------------
__global__ __launch_bounds__(256) void k3_mfma(const float* __restrict__ x,
                                               const unsigned short* __restrict__ wt,
                                               const float* __restrict__ add_i,
                                               const float* __restrict__ add_j,
                                               const float* __restrict__ add_d,
                                               float* __restrict__ out) {
    __shared__ unsigned short Al[64 * KP];   // 13312 B
    const int rawx = blockIdx.x;             // 0..639
    const int idx  = (rawx & 7) * 80 + (rawx >> 3);   // XCD-chunked (bijective)
    const int b    = blockIdx.y;
    const int p    = idx >> 6;               // 0..9 pair id
    const int io   = idx & 63;
    int It, Jt;
    if (p < 4)      { It = 0; Jt = p; }
    else if (p < 7) { It = 1; Jt = p - 3; }
    else if (p < 9) { It = 2; Jt = p - 5; }
    else            { It = 3; Jt = 3; }
    const int i  = It * 64 + io;
    const int J  = Jt * 64;
    const int bi = b * Nx + i;
    const int t  = threadIdx.x;

    // stage A: row r = t/4, quarter q = t&3 — HW packed bf16 convert
    {
        const int r = t >> 2, q = t & 3;
        const float* pij = x + ((size_t)bi * Nx + J + r) * Lx;
        const float* pji = x + ((size_t)(b * Nx + J + r) * Nx + i) * Lx;
        unsigned int* arow = (unsigned int*)Al + r * (KP / 2);
        #pragma unroll
        for (int e = 0; e < 3; ++e) {
            const float4 v = *(const float4*)(pij + q * 4 + e * 16);
            arow[q * 2 + e * 8 + 0] = cvt_pk_bf16(v.x, v.y);
            arow[q * 2 + e * 8 + 1] = cvt_pk_bf16(v.z, v.w);
        }
        #pragma unroll
        for (int e = 0; e < 3; ++e) {
            const float4 v = *(const float4*)(pji + q * 4 + e * 16);
            arow[24 + q * 2 + e * 8 + 0] = cvt_pk_bf16(v.x, v.y);
            arow[24 + q * 2 + e * 8 + 1] = cvt_pk_bf16(v.z, v.w);
        }
    }
    __syncthreads();

    const int wave = t >> 6, lane = t & 63;
    const int lm = lane & 15, quad = lane >> 4;
    const int n0 = wave * 16;                // this wave's 16-j N-tile
    const bool offd = (It != Jt);
    const int j = J + n0 + lm;               // out col (pass0) / out row (pass1)

    const float* aiP = add_i + (size_t)bi * Fx;
    const float* ajP = add_j + (size_t)bi * Fx;
    const float* adP = add_d + (size_t)bi * Fx;
    float* outP = out + (size_t)bi * Nx * Fx;
    const bool isdiag = (!offd) && (j == i);

    // x fragments (B operand) for both passes loaded once (mirror = halves swapped)
    bf16x8 afr0[3], afr1[3];
    #pragma unroll
    for (int ks = 0; ks < 3; ++ks) {
        const int off = ks * 32 + quad * 8;
        afr0[ks] = *(const bf16x8*)(Al + (n0 + lm) * KP + off);
    }
    if (offd) {
        #pragma unroll
        for (int ks = 0; ks < 3; ++ks) {
            const int off  = ks * 32 + quad * 8;
            const int offm = (off < 48) ? off + 48 : off - 48;
            afr1[ks] = *(const bf16x8*)(Al + (n0 + lm) * KP + offm);
        }
    }

    #pragma unroll
    for (int nt = 0; nt < 6; ++nt) {
        bf16x8 bfr[3];                       // w fragments (A operand) from L2
        #pragma unroll
        for (int ks = 0; ks < 3; ++ks)
            bfr[ks] = *(const bf16x8*)(wt + (nt * 16 + lm) * KP + ks * 32 + quad * 8);
        const int f0 = nt * 16 + quad * 4;

        f32x4 c0 = {0.f, 0.f, 0.f, 0.f};
        #pragma unroll
        for (int ks = 0; ks < 3; ++ks)
            c0 = __builtin_amdgcn_mfma_f32_16x16x32_bf16(bfr[ks], afr0[ks], c0, 0, 0, 0);
        {
            const float4 ai4 = *(const float4*)(aiP + f0);
            const float4 aj4 = *(const float4*)(add_j + ((size_t)(b * Nx) + j) * Fx + f0);
            f32x4 o;
            o[0] = c0[0] + ai4.x + aj4.x;
            o[1] = c0[1] + ai4.y + aj4.y;
            o[2] = c0[2] + ai4.z + aj4.z;
            o[3] = c0[3] + ai4.w + aj4.w;
            if (isdiag) {
                const float4 ad4 = *(const float4*)(adP + f0);
                o[0] += ad4.x; o[1] += ad4.y; o[2] += ad4.z; o[3] += ad4.w;
            }
            __builtin_nontemporal_store(o, (f32x4*)(outP + (size_t)j * Fx + f0));
        }
        if (offd) {
            f32x4 c1 = {0.f, 0.f, 0.f, 0.f};
            #pragma unroll
            for (int ks = 0; ks < 3; ++ks)
                c1 = __builtin_amdgcn_mfma_f32_16x16x32_bf16(bfr[ks], afr1[ks], c1, 0, 0, 0);
            const float4 aj4 = *(const float4*)(ajP + f0);
            const float4 ai4 = *(const float4*)(add_i + ((size_t)(b * Nx) + j) * Fx + f0);
            f32x4 o;
            o[0] = c1[0] + aj4.x + ai4.x;
            o[1] = c1[1] + aj4.y + ai4.y;
            o[2] = c1[2] + aj4.z + ai4.z;
            o[3] = c1[3] + aj4.w + ai4.w;
            __builtin_nontemporal_store(o, (f32x4*)(out + ((size_t)(b * Nx + j) * Nx + i) * Fx + f0));
        }
    }
}

// ---------------------------------------------------------------------------
extern "C" void kernel_launch(void* const* d_in, const int* in_sizes, int n_in,
                              void* d_out, int out_size, void* d_ws, size_t ws_size,
                              hipStream_t stream) {
    const float* x = (const float*)d_in[0];
    const float* w = (const float*)d_in[1];
    float* out = (float*)d_out;

    // ws layout: zeroed region FIRST (trace | totsum), then the rest
    float* ws      = (float*)d_ws;
    float* trace   = ws;                                  // B*L
    float* totsum  = trace  + (size_t)Bx * Lx;            // B*L
    float* rowsum  = totsum + (size_t)Bx * Lx;            // B*N*L
    float* diagv   = rowsum + (size_t)Bx * Nx * Lx;       // B*N*L
    float* part    = diagv  + (size_t)Bx * Nx * Lx;       // 512 * N*L colsum partials
    float* add_i   = part   + (size_t)512 * Nx * Lx;      // B*N*F
    float* add_j   = add_i  + (size_t)Bx * Nx * Fx;
    float* add_d   = add_j  + (size_t)Bx * Nx * Fx;
    unsigned short* wtbf = (unsigned short*)(add_d + (size_t)Bx * Nx * Fx);

    (void)hipMemsetAsync(ws, 0, (size_t)2 * Bx * Lx * sizeof(float), stream);
    kA_fused<<<512 + 52, 192, 0, stream>>>(x, w, rowsum, part, diagv,
                                           trace, totsum, wtbf);
    k2_vectors<<<512, 192, 0, stream>>>(w, rowsum, part, diagv, trace, totsum,
                                        add_i, add_j, add_d);
    dim3 g3(640, Bx);
    k3_mfma<<<g3, 256, 0, stream>>>(x, wtbf, add_i, add_j, add_d, out);
}

// Round 6
// 367.533 us; speedup vs baseline: 1.0332x; 1.0332x over previous
//
#include <hip/hip_runtime.h>

#define Bx 8
#define Nx 256
#define Lx 48
#define Fx 96
#define KP 104     // padded K stride in bf16 units (208 B, 16B-aligned)

typedef __attribute__((ext_vector_type(8))) short bf16x8;
typedef __attribute__((ext_vector_type(4))) float f32x4;

__device__ __forceinline__ unsigned short f2bf(float f) {
    unsigned int u = __float_as_uint(f);
    u += 0x7fffu + ((u >> 16) & 1u);       // RNE
    return (unsigned short)(u >> 16);
}
// HW packed fp32->bf16 (RNE): lo = a, hi = b.
__device__ __forceinline__ unsigned int cvt_pk_bf16(float a, float b) {
    unsigned int r;
    asm("v_cvt_pk_bf16_f32 %0, %1, %2" : "=v"(r) : "v"(a), "v"(b));
    return r;
}

// ---------------------------------------------------------------------------
// kA: SINGLE pass over x (round-3 proven version).  Block roles:
//  role R (blk < 512): block = (b, 4-i-chunk). float4-vectorized read of the
//    4 rows; computes rowsum (LDS reduce), diag, trace/totsum (atomics, tiny),
//    and a per-block colsum PARTIAL tile written with plain coalesced stores
//    (part[ic*8+b][j*48+l]).  No colsum atomics at all.
//  role W (512..563): bf16 repack of w11/w12 into wt[f][KP].
// trace/totsum (3 KB) must be zeroed first.
// ---------------------------------------------------------------------------
__global__ __launch_bounds__(192) void kA_fused(const float* __restrict__ x,
                                                const float* __restrict__ w,
                                                float* __restrict__ rowsum,
                                                float* __restrict__ part,
                                                float* __restrict__ diagv,
                                                float* __restrict__ trace,
                                                float* __restrict__ totsum,
                                                unsigned short* __restrict__ wt) {
    const int blk = blockIdx.x;
    const int t = threadIdx.x;
    if (blk < 512) {
        const int b  = blk >> 6;
        const int ic = blk & 63;
        const int i0 = ic * 4;
        // thread -> (jg, l-quad): stride 192 floats * 4 = 768 = 16*48, so each
        // thread's l-quad is CONSTANT: l4 = 4*(t%12), j = (t/12) + 16*it.
        const int jg = t / 12;
        const int l4 = (t % 12) * 4;
        const size_t xb = ((size_t)(b * Nx + i0)) * Nx * Lx;
        float* __restrict__ pp = part + ((size_t)(ic * 8 + b)) * (Nx * Lx);

        float4 r0 = {0.f,0.f,0.f,0.f}, r1 = r0, r2 = r0, r3 = r0;
        #pragma unroll
        for (int it = 0; it < 16; ++it) {
            const int j = jg + 16 * it;
            const size_t off = (size_t)j * Lx + l4;
            const float4 v0 = *(const float4*)(x + xb + off);
            const float4 v1 = *(const float4*)(x + xb + (size_t)Nx * Lx + off);
            const float4 v2 = *(const float4*)(x + xb + 2 * (size_t)Nx * Lx + off);
            const float4 v3 = *(const float4*)(x + xb + 3 * (size_t)Nx * Lx + off);
            r0.x += v0.x; r0.y += v0.y; r0.z += v0.z; r0.w += v0.w;
            r1.x += v1.x; r1.y += v1.y; r1.z += v1.z; r1.w += v1.w;
            r2.x += v2.x; r2.y += v2.y; r2.z += v2.z; r2.w += v2.w;
            r3.x += v3.x; r3.y += v3.y; r3.z += v3.z; r3.w += v3.w;
            float4 cs;
            cs.x = (v0.x + v1.x) + (v2.x + v3.x);
            cs.y = (v0.y + v1.y) + (v2.y + v3.y);
            cs.z = (v0.z + v1.z) + (v2.z + v3.z);
            cs.w = (v0.w + v1.w) + (v2.w + v3.w);
            *(float4*)(pp + off) = cs;
        }
        // rowsum reduction: red[row][thread] float4, then (row,l) threads sum 16 jg's
        __shared__ float4 red[768];
        red[        t] = r0;
        red[192  + t] = r1;
        red[384  + t] = r2;
        red[576  + t] = r3;
        __syncthreads();
        {
            const int r = t / 48, l = t % 48;
            const float* rr = (const float*)(red + r * 192);
            float s = 0.f;
            #pragma unroll
            for (int g = 0; g < 16; ++g)
                s += rr[(g * 12 + (l >> 2)) * 4 + (l & 3)];
            const size_t ri = ((size_t)(b * Nx + i0 + r)) * Lx + l;
            rowsum[ri] = s;
            atomicAdd(totsum + b * Lx + l, s);
            const float dv = x[(((size_t)(b * Nx + i0 + r)) * Nx + (i0 + r)) * Lx + l];
            diagv[ri] = dv;
            atomicAdd(trace + b * Lx + l, dv);
        }
    } else {
        // ---- w role: 52 blocks * 192 = 9984 = Fx*KP exactly
        const int idx = (blk - 512) * 192 + t;
        const int f = idx / KP, kk = idx % KP;
        float v = 0.f;
        if (kk < 48)      v = w[12 * Lx * Fx + kk * Fx + f];
        else if (kk < 96) v = w[11 * Lx * Fx + (kk - 48) * Fx + f];
        wt[idx] = f2bf(v);
    }
}

// ---------------------------------------------------------------------------
// K2: per-(b,n) f-vectors (fp32 exact, round-3 proven version). Prologue
// reduces the 64 colsum partials for this block's 4 n-rows into LDS;
// colsum never exists globally.
// ---------------------------------------------------------------------------
__global__ __launch_bounds__(192) void k2_vectors(const float* __restrict__ w,
                                                  const float* __restrict__ rowsum,
                                                  const float* __restrict__ part,
                                                  const float* __restrict__ diagv,
                                                  const float* __restrict__ trace,
                                                  const float* __restrict__ totsum,
                                                  float* __restrict__ add_i,
                                                  float* __restrict__ add_j,
                                                  float* __restrict__ add_d) {
    const int blk = blockIdx.x;            // 0..511
    const int t = threadIdx.x;             // 0..191
    const int b  = blk >> 6;
    const int n0 = (blk & 63) * 4;
    __shared__ float csh[192];             // colsum for the block's 4 rows
    {
        const size_t e0 = (size_t)n0 * Lx + t;
        float s = 0.f;
        #pragma unroll 8
        for (int ic = 0; ic < 64; ++ic)
            s += part[((size_t)(ic * 8 + b)) * (Nx * Lx) + e0];
        csh[t] = s;
    }
    __syncthreads();

    const int f  = t % Fx;
    const int nh = t / Fx;                 // 0 or 1
    const int nb = b * Nx + n0 + nh * 2;   // first of this thread's 2 n-rows
    const float* trP = trace  + b * Lx;
    const float* tsP = totsum + b * Lx;

    float ai[2] = {0.f, 0.f}, aj[2] = {0.f, 0.f}, ad[2] = {0.f, 0.f};
    float sd = 0.f, si = 0.f;
    for (int l = 0; l < Lx; ++l) {
        const float* wl = w + (size_t)l * Fx + f;
        const float w0  = wl[0];
        const float w1  = wl[1  * Lx * Fx];
        const float w2  = wl[2  * Lx * Fx];
        const float w3  = wl[3  * Lx * Fx];
        const float w4  = wl[4  * Lx * Fx];
        const float w5  = wl[5  * Lx * Fx];
        const float w6  = wl[6  * Lx * Fx];
        const float w7  = wl[7  * Lx * Fx];
        const float w8  = wl[8  * Lx * Fx];
        const float w9  = wl[9  * Lx * Fx];
        const float w10 = wl[10 * Lx * Fx];
        const float w13 = wl[13 * Lx * Fx];
        const float w14 = wl[14 * Lx * Fx];
        const float tr = trP[l], ts = tsP[l];
        sd = fmaf(tr, w3,  sd); sd = fmaf(ts, w4,  sd);
        si = fmaf(tr, w13, si); si = fmaf(ts, w14, si);
        #pragma unroll
        for (int nn = 0; nn < 2; ++nn) {
            const size_t ix = (size_t)(nb + nn) * Lx + l;
            const float d = diagv[ix], r = rowsum[ix];
            const float c = csh[(nh * 2 + nn) * Lx + l];
            ad[nn] = fmaf(d, w0, ad[nn]); ad[nn] = fmaf(r, w1, ad[nn]); ad[nn] = fmaf(c, w2,  ad[nn]);
            aj[nn] = fmaf(d, w5, aj[nn]); aj[nn] = fmaf(r, w6, aj[nn]); aj[nn] = fmaf(c, w7,  aj[nn]);
            ai[nn] = fmaf(d, w8, ai[nn]); ai[nn] = fmaf(r, w9, ai[nn]); ai[nn] = fmaf(c, w10, ai[nn]);
        }
    }
    #pragma unroll
    for (int nn = 0; nn < 2; ++nn) {
        const size_t idx = (size_t)(nb + nn) * Fx + f;
        add_d[idx] = ad[nn] + sd;
        add_j[idx] = aj[nn];
        add_i[idx] = ai[nn] + si;
    }
}

// ---------------------------------------------------------------------------
// K3: MFMA dense pass (round-3 proven structure: Bl LDS staging RESTORED —
// round-5 showed global w-frag reads cost ~12 µs).  Mirror-pair reuse,
// swapped operand order (A = w-frag, B = x-frag) -> float4 NT epilogue.
// Only change vs round-3: stage-A x loads (long L3 latency) issued BEFORE
// the stage-B wt copy (L2-hot) so A-latency overlaps B-staging; both are
// guarded by the same barrier as before.
// ---------------------------------------------------------------------------
__global__ __launch_bounds__(256) void k3_mfma(const float* __restrict__ x,
                                               const unsigned short* __restrict__ wt,
                                               const float* __restrict__ add_i,
                                               const float* __restrict__ add_j,
                                               const float* __restrict__ add_d,
                                               float* __restrict__ out) {
    __shared__ unsigned short Al[64 * KP];   // 13312 B
    __shared__ unsigned short Bl[96 * KP];   // 19968 B
    const int rawx = blockIdx.x;             // 0..639
    const int idx  = (rawx & 7) * 80 + (rawx >> 3);   // XCD-chunked (bijective)
    const int b    = blockIdx.y;
    const int p    = idx >> 6;               // 0..9 pair id
    const int io   = idx & 63;
    int It, Jt;
    if (p < 4)      { It = 0; Jt = p; }
    else if (p < 7) { It = 1; Jt = p - 3; }
    else if (p < 9) { It = 2; Jt = p - 5; }
    else            { It = 3; Jt = 3; }
    const int i  = It * 64 + io;
    const int J  = Jt * 64;
    const int bi = b * Nx + i;
    const int t  = threadIdx.x;

    // stage A first (x loads have L3 latency; overlap them with stage B below)
    {
        const int r = t >> 2, q = t & 3;
        const float* pij = x + ((size_t)bi * Nx + J + r) * Lx;
        const float* pji = x + ((size_t)(b * Nx + J + r) * Nx + i) * Lx;
        unsigned int* arow = (unsigned int*)Al + r * (KP / 2);
        #pragma unroll
        for (int e = 0; e < 3; ++e) {
            const float4 v = *(const float4*)(pij + q * 4 + e * 16);
            arow[q * 2 + e * 8 + 0] = cvt_pk_bf16(v.x, v.y);
            arow[q * 2 + e * 8 + 1] = cvt_pk_bf16(v.z, v.w);
        }
        #pragma unroll
        for (int e = 0; e < 3; ++e) {
            const float4 v = *(const float4*)(pji + q * 4 + e * 16);
            arow[24 + q * 2 + e * 8 + 0] = cvt_pk_bf16(v.x, v.y);
            arow[24 + q * 2 + e * 8 + 1] = cvt_pk_bf16(v.z, v.w);
        }
    }
    // stage B: 96*KP bf16 = 1248 uint4 (L2-hot broadcast)
    {
        const uint4* src = (const uint4*)wt;
        uint4* dst = (uint4*)Bl;
        #pragma unroll
        for (int it = 0; it < 5; ++it) {
            const int k = t + it * 256;
            if (k < (96 * KP * 2) / 16) dst[k] = src[k];
        }
    }
    __syncthreads();

    const int wave = t >> 6, lane = t & 63;
    const int lm = lane & 15, quad = lane >> 4;
    const int n0 = wave * 16;                // this wave's 16-j N-tile
    const bool offd = (It != Jt);
    const int j = J + n0 + lm;               // out col (pass0) / out row (pass1)

    const float* aiP = add_i + (size_t)bi * Fx;
    const float* ajP = add_j + (size_t)bi * Fx;
    const float* adP = add_d + (size_t)bi * Fx;
    float* outP = out + (size_t)bi * Nx * Fx;
    const bool isdiag = (!offd) && (j == i);

    // x fragments (B operand) for both passes loaded once (mirror = halves swapped)
    bf16x8 afr0[3], afr1[3];
    #pragma unroll
    for (int ks = 0; ks < 3; ++ks) {
        const int off = ks * 32 + quad * 8;
        afr0[ks] = *(const bf16x8*)(Al + (n0 + lm) * KP + off);
    }
    if (offd) {
        #pragma unroll
        for (int ks = 0; ks < 3; ++ks) {
            const int off  = ks * 32 + quad * 8;
            const int offm = (off < 48) ? off + 48 : off - 48;
            afr1[ks] = *(const bf16x8*)(Al + (n0 + lm) * KP + offm);
        }
    }

    #pragma unroll
    for (int nt = 0; nt < 6; ++nt) {
        bf16x8 bfr[3];                       // w fragments (A operand)
        #pragma unroll
        for (int ks = 0; ks < 3; ++ks)
            bfr[ks] = *(const bf16x8*)(Bl + (nt * 16 + lm) * KP + ks * 32 + quad * 8);
        const int f0 = nt * 16 + quad * 4;

        f32x4 c0 = {0.f, 0.f, 0.f, 0.f};
        #pragma unroll
        for (int ks = 0; ks < 3; ++ks)
            c0 = __builtin_amdgcn_mfma_f32_16x16x32_bf16(bfr[ks], afr0[ks], c0, 0, 0, 0);
        {
            const float4 ai4 = *(const float4*)(aiP + f0);
            const float4 aj4 = *(const float4*)(add_j + ((size_t)(b * Nx) + j) * Fx + f0);
            f32x4 o;
            o[0] = c0[0] + ai4.x + aj4.x;
            o[1] = c0[1] + ai4.y + aj4.y;
            o[2] = c0[2] + ai4.z + aj4.z;
            o[3] = c0[3] + ai4.w + aj4.w;
            if (isdiag) {
                const float4 ad4 = *(const float4*)(adP + f0);
                o[0] += ad4.x; o[1] += ad4.y; o[2] += ad4.z; o[3] += ad4.w;
            }
            __builtin_nontemporal_store(o, (f32x4*)(outP + (size_t)j * Fx + f0));
        }
        if (offd) {
            f32x4 c1 = {0.f, 0.f, 0.f, 0.f};
            #pragma unroll
            for (int ks = 0; ks < 3; ++ks)
                c1 = __builtin_amdgcn_mfma_f32_16x16x32_bf16(bfr[ks], afr1[ks], c1, 0, 0, 0);
            const float4 aj4 = *(const float4*)(ajP + f0);
            const float4 ai4 = *(const float4*)(add_i + ((size_t)(b * Nx) + j) * Fx + f0);
            f32x4 o;
            o[0] = c1[0] + aj4.x + ai4.x;
            o[1] = c1[1] + aj4.y + ai4.y;
            o[2] = c1[2] + aj4.z + ai4.z;
            o[3] = c1[3] + aj4.w + ai4.w;
            __builtin_nontemporal_store(o, (f32x4*)(out + ((size_t)(b * Nx + j) * Nx + i) * Fx + f0));
        }
    }
}

// ---------------------------------------------------------------------------
extern "C" void kernel_launch(void* const* d_in, const int* in_sizes, int n_in,
                              void* d_out, int out_size, void* d_ws, size_t ws_size,
                              hipStream_t stream) {
    const float* x = (const float*)d_in[0];
    const float* w = (const float*)d_in[1];
    float* out = (float*)d_out;

    // ws layout: zeroed region FIRST (trace | totsum), then the rest
    float* ws      = (float*)d_ws;
    float* trace   = ws;                                  // B*L
    float* totsum  = trace  + (size_t)Bx * Lx;            // B*L
    float* rowsum  = totsum + (size_t)Bx * Lx;            // B*N*L
    float* diagv   = rowsum + (size_t)Bx * Nx * Lx;       // B*N*L
    float* part    = diagv  + (size_t)Bx * Nx * Lx;       // 512 * N*L colsum partials
    float* add_i   = part   + (size_t)512 * Nx * Lx;      // B*N*F
    float* add_j   = add_i  + (size_t)Bx * Nx * Fx;
    float* add_d   = add_j  + (size_t)Bx * Nx * Fx;
    unsigned short* wtbf = (unsigned short*)(add_d + (size_t)Bx * Nx * Fx);

    (void)hipMemsetAsync(ws, 0, (size_t)2 * Bx * Lx * sizeof(float), stream);
    kA_fused<<<512 + 52, 192, 0, stream>>>(x, w, rowsum, part, diagv,
                                           trace, totsum, wtbf);
    k2_vectors<<<512, 192, 0, stream>>>(w, rowsum, part, diagv, trace, totsum,
                                        add_i, add_j, add_d);
    dim3 g3(640, Bx);
    k3_mfma<<<g3, 256, 0, stream>>>(x, wtbf, add_i, add_j, add_d, out);
}